// Round 5
// baseline (374.284 us; speedup 1.0000x reference)
//
#include <hip/hip_runtime.h>
#include <cstddef>

// ---- bf16 pack/unpack helpers (RNE) ----
__device__ inline unsigned pack_bf16x2(float a, float b) {
    unsigned ua = __float_as_uint(a), ub = __float_as_uint(b);
    ua = (ua + 0x7FFFu + ((ua >> 16) & 1u)) >> 16;
    ub = (ub + 0x7FFFu + ((ub >> 16) & 1u)) >> 16;
    return ua | (ub << 16);
}
__device__ inline float bf_lo(unsigned u) { return __uint_as_float(u << 16); }
__device__ inline float bf_hi(unsigned u) { return __uint_as_float(u & 0xFFFF0000u); }

// ---------------- degree / norm ----------------
__global__ __launch_bounds__(256) void k_deg_init(int* __restrict__ deg, int n) {
    int i = blockIdx.x * 256 + threadIdx.x;
    if (i < n) deg[i] = 1;   // self-loop contributes 1
}

__global__ __launch_bounds__(256) void k_deg_count(const int* __restrict__ dst, int* __restrict__ deg, int e) {
    int i = blockIdx.x * 256 + threadIdx.x;
    if (i < e) atomicAdd(&deg[dst[i]], 1);
}

// ---------------- scan1: per-block exclusive scan of (deg-1); also emits dinv ----------------
__global__ __launch_bounds__(256) void k_scan1(const int* __restrict__ deg, float* __restrict__ dinv,
                                               int* __restrict__ off, int* __restrict__ partial, int N) {
    __shared__ int sh[256];
    int i = blockIdx.x * 256 + threadIdx.x;
    int d0 = (i < N) ? deg[i] : 1;
    if (i < N) dinv[i] = rsqrtf((float)d0);
    int v = (i < N) ? (d0 - 1) : 0;
    sh[threadIdx.x] = v;
    __syncthreads();
    for (int d = 1; d < 256; d <<= 1) {
        int t = (threadIdx.x >= d) ? sh[threadIdx.x - d] : 0;
        __syncthreads();
        sh[threadIdx.x] += t;
        __syncthreads();
    }
    if (i < N) off[i] = sh[threadIdx.x] - v;           // exclusive
    if (threadIdx.x == 255) partial[blockIdx.x] = sh[255];
}

__global__ __launch_bounds__(256) void k_scan2(int* __restrict__ partial, int nb) {
    __shared__ int sh[256];
    int v = (threadIdx.x < nb) ? partial[threadIdx.x] : 0;
    sh[threadIdx.x] = v;
    __syncthreads();
    for (int d = 1; d < 256; d <<= 1) {
        int t = (threadIdx.x >= d) ? sh[threadIdx.x - d] : 0;
        __syncthreads();
        sh[threadIdx.x] += t;
        __syncthreads();
    }
    if (threadIdx.x < nb) partial[threadIdx.x] = sh[threadIdx.x] - v;  // exclusive
}

__global__ __launch_bounds__(256) void k_scan3(int* __restrict__ off, const int* __restrict__ partial,
                                               int* __restrict__ cursor, int N) {
    int i = blockIdx.x * 256 + threadIdx.x;
    if (i < N) {
        int o = off[i] + partial[blockIdx.x];
        off[i] = o;
        cursor[i] = o;
    }
}

// ---------------- bucket edges by dst: esrc[p] = src  (4B entries) ----------------
__global__ __launch_bounds__(256) void k_bucket(const int* __restrict__ src, const int* __restrict__ dst,
                                                int* __restrict__ cursor, int* __restrict__ esrc, int E) {
    int e = blockIdx.x * 256 + threadIdx.x;
    if (e >= E) return;
    int s = src[e], d = dst[e];
    int p = atomicAdd(&cursor[d], 1);
    esrc[p] = s;
}

// ---------------- GEMM1: xwb[M,128](bf16) = x[M,128] @ W[128,128] ----------------
__global__ __launch_bounds__(256) void k_gemm1(const float* __restrict__ x, const float* __restrict__ W,
                                               unsigned* __restrict__ xwb, int M) {
    __shared__ float ws[128 * 128];      // ws[k*128 + c]
    __shared__ float xs[128][32];        // xs[k][r]  (transposed tile)
    const int tid  = threadIdx.x;
    const int row0 = blockIdx.x * 32;

    for (int i = tid * 4; i < 128 * 128; i += 1024)
        *(float4*)&ws[i] = *(const float4*)&W[i];

    for (int i = tid; i < 32 * 32; i += 256) {
        int r  = i >> 5;
        int cc = (i & 31) << 2;
        float4 v = make_float4(0.f, 0.f, 0.f, 0.f);
        if (row0 + r < M) v = *(const float4*)&x[(size_t)(row0 + r) * 128 + cc];
        xs[cc + 0][r] = v.x; xs[cc + 1][r] = v.y; xs[cc + 2][r] = v.z; xs[cc + 3][r] = v.w;
    }
    __syncthreads();

    const int c0 = (tid & 31) << 2;      // 4 cols
    const int r0 = (tid >> 5) << 2;      // 4 rows
    float4 a0 = {0,0,0,0}, a1 = {0,0,0,0}, a2 = {0,0,0,0}, a3 = {0,0,0,0};
#pragma unroll 8
    for (int k = 0; k < 128; ++k) {
        float4 wv = *(const float4*)&ws[k * 128 + c0];
        float4 xv = *(const float4*)&xs[k][r0];
        a0.x += xv.x * wv.x; a0.y += xv.x * wv.y; a0.z += xv.x * wv.z; a0.w += xv.x * wv.w;
        a1.x += xv.y * wv.x; a1.y += xv.y * wv.y; a1.z += xv.y * wv.z; a1.w += xv.y * wv.w;
        a2.x += xv.z * wv.x; a2.y += xv.z * wv.y; a2.z += xv.z * wv.z; a2.w += xv.z * wv.w;
        a3.x += xv.w * wv.x; a3.y += xv.w * wv.y; a3.z += xv.w * wv.z; a3.w += xv.w * wv.w;
    }
    // write packed bf16: uint2 per (row, 4-col group)
    uint2* o = (uint2*)xwb;
    if (row0 + r0 + 0 < M) o[(size_t)(row0 + r0 + 0) * 32 + (c0 >> 2)] = make_uint2(pack_bf16x2(a0.x, a0.y), pack_bf16x2(a0.z, a0.w));
    if (row0 + r0 + 1 < M) o[(size_t)(row0 + r0 + 1) * 32 + (c0 >> 2)] = make_uint2(pack_bf16x2(a1.x, a1.y), pack_bf16x2(a1.z, a1.w));
    if (row0 + r0 + 2 < M) o[(size_t)(row0 + r0 + 2) * 32 + (c0 >> 2)] = make_uint2(pack_bf16x2(a2.x, a2.y), pack_bf16x2(a2.z, a2.w));
    if (row0 + r0 + 3 < M) o[(size_t)(row0 + r0 + 3) * 32 + (c0 >> 2)] = make_uint2(pack_bf16x2(a3.x, a3.y), pack_bf16x2(a3.z, a3.w));
}

// ---------------- GEMM2: hwb[M,64](bf16) = relu(h[M,128]) @ W[128,64] ----------------
__global__ __launch_bounds__(256) void k_gemm2(const float* __restrict__ h_in, const float* __restrict__ W,
                                               unsigned* __restrict__ hwb, int M) {
    __shared__ float ws[128 * 64];       // ws[k*64 + c]
    __shared__ float xs[128][32];        // xs[k][r]
    const int tid  = threadIdx.x;
    const int row0 = blockIdx.x * 32;

    for (int i = tid * 4; i < 128 * 64; i += 1024)
        *(float4*)&ws[i] = *(const float4*)&W[i];

    for (int i = tid; i < 32 * 32; i += 256) {
        int r  = i >> 5;
        int cc = (i & 31) << 2;
        float4 v = make_float4(0.f, 0.f, 0.f, 0.f);
        if (row0 + r < M) {
            v = *(const float4*)&h_in[(size_t)(row0 + r) * 128 + cc];
            v.x = fmaxf(v.x, 0.f); v.y = fmaxf(v.y, 0.f);
            v.z = fmaxf(v.z, 0.f); v.w = fmaxf(v.w, 0.f);
        }
        xs[cc + 0][r] = v.x; xs[cc + 1][r] = v.y; xs[cc + 2][r] = v.z; xs[cc + 3][r] = v.w;
    }
    __syncthreads();

    const int c0 = (tid & 15) << 2;      // 4 cols of 64
    const int r0 = (tid >> 4) << 1;      // 2 rows
    float4 a0 = {0,0,0,0}, a1 = {0,0,0,0};
#pragma unroll 8
    for (int k = 0; k < 128; ++k) {
        float4 wv = *(const float4*)&ws[k * 64 + c0];
        float2 xv = *(const float2*)&xs[k][r0];
        a0.x += xv.x * wv.x; a0.y += xv.x * wv.y; a0.z += xv.x * wv.z; a0.w += xv.x * wv.w;
        a1.x += xv.y * wv.x; a1.y += xv.y * wv.y; a1.z += xv.y * wv.z; a1.w += xv.y * wv.w;
    }
    uint2* o = (uint2*)hwb;
    if (row0 + r0 + 0 < M) o[(size_t)(row0 + r0 + 0) * 16 + (c0 >> 2)] = make_uint2(pack_bf16x2(a0.x, a0.y), pack_bf16x2(a0.z, a0.w));
    if (row0 + r0 + 1 < M) o[(size_t)(row0 + r0 + 1) * 16 + (c0 >> 2)] = make_uint2(pack_bf16x2(a1.x, a1.y), pack_bf16x2(a1.z, a1.w));
}

// ---------------- pull aggregation, layer1 (bf16 gather, 4B edge entries) ----------------
// One wave per node; two 32-lane halves; each lane covers 4 cols via uint2 (8B).
// Lane computes w for its own edge (dinv gather, L2-hit), then shfl {s,w}.
__global__ __launch_bounds__(256) void k_agg1(const uint2* __restrict__ xwb, const int* __restrict__ esrc,
                                              const int* __restrict__ off, const int* __restrict__ deg,
                                              const float* __restrict__ dinv, const float* __restrict__ b,
                                              float* __restrict__ out1, int N) {
    const int node = blockIdx.x * 4 + (threadIdx.x >> 6);
    if (node >= N) return;
    const int lane = threadIdx.x & 63;
    const int half = lane >> 5;          // 0 or 1
    const int lc   = lane & 31;          // uint2 index within row
    const int c0   = lc << 2;            // first of 4 cols

    const float di = dinv[node];
    float4 acc0 = {0,0,0,0}, acc1 = {0,0,0,0}, acc2 = {0,0,0,0}, acc3 = {0,0,0,0};
    if (half == 0) {                     // self-loop + bias on half 0 only
        float w0 = di * di;
        uint2  sv = xwb[(size_t)node * 32 + lc];
        float4 bb = *(const float4*)&b[c0];
        acc0.x = bb.x + bf_lo(sv.x) * w0; acc0.y = bb.y + bf_hi(sv.x) * w0;
        acc0.z = bb.z + bf_lo(sv.y) * w0; acc0.w = bb.w + bf_hi(sv.y) * w0;
    }

    const int base = off[node];
    const int cnt  = deg[node] - 1;      // real (non-self) in-edges
    for (int p0 = 0; p0 < cnt; p0 += 64) {
        int   es = 0;                    // sentinel: row 0
        float ew = 0.f;                  // sentinel: weight 0
        if (p0 + lane < cnt) {
            es = esrc[base + p0 + lane];
            ew = dinv[es] * di;
        }
        const int take = min(64, cnt - p0);
        int j = 0;
        for (; j + 8 <= take; j += 8) {
            int i0 = j + half, i1 = j + 2 + half, i2 = j + 4 + half, i3 = j + 6 + half;
            int   s0 = __shfl(es, i0); float w0f = __shfl(ew, i0);
            int   s1 = __shfl(es, i1); float w1f = __shfl(ew, i1);
            int   s2 = __shfl(es, i2); float w2f = __shfl(ew, i2);
            int   s3 = __shfl(es, i3); float w3f = __shfl(ew, i3);
            uint2 v0 = xwb[(size_t)s0 * 32 + lc];
            uint2 v1 = xwb[(size_t)s1 * 32 + lc];
            uint2 v2 = xwb[(size_t)s2 * 32 + lc];
            uint2 v3 = xwb[(size_t)s3 * 32 + lc];
            acc0.x += bf_lo(v0.x) * w0f; acc0.y += bf_hi(v0.x) * w0f;
            acc0.z += bf_lo(v0.y) * w0f; acc0.w += bf_hi(v0.y) * w0f;
            acc1.x += bf_lo(v1.x) * w1f; acc1.y += bf_hi(v1.x) * w1f;
            acc1.z += bf_lo(v1.y) * w1f; acc1.w += bf_hi(v1.y) * w1f;
            acc2.x += bf_lo(v2.x) * w2f; acc2.y += bf_hi(v2.x) * w2f;
            acc2.z += bf_lo(v2.y) * w2f; acc2.w += bf_hi(v2.y) * w2f;
            acc3.x += bf_lo(v3.x) * w3f; acc3.y += bf_hi(v3.x) * w3f;
            acc3.z += bf_lo(v3.y) * w3f; acc3.w += bf_hi(v3.y) * w3f;
        }
        for (; j < take; j += 2) {
            int i0 = j + half;           // may hit a sentinel lane (w=0) — safe
            int   s0 = __shfl(es, i0); float w0f = __shfl(ew, i0);
            uint2 v0 = xwb[(size_t)s0 * 32 + lc];
            acc0.x += bf_lo(v0.x) * w0f; acc0.y += bf_hi(v0.x) * w0f;
            acc0.z += bf_lo(v0.y) * w0f; acc0.w += bf_hi(v0.y) * w0f;
        }
    }
    acc0.x += acc1.x + acc2.x + acc3.x;
    acc0.y += acc1.y + acc2.y + acc3.y;
    acc0.z += acc1.z + acc2.z + acc3.z;
    acc0.w += acc1.w + acc2.w + acc3.w;
    acc0.x += __shfl_xor(acc0.x, 32);
    acc0.y += __shfl_xor(acc0.y, 32);
    acc0.z += __shfl_xor(acc0.z, 32);
    acc0.w += __shfl_xor(acc0.w, 32);
    if (half == 0) *(float4*)&out1[(size_t)node * 128 + c0] = acc0;
}

// ---------------- pull aggregation, layer2 (bf16 gather, 4B edge entries) ----------------
// One wave per node, four 16-lane groups; lane covers 4 of 64 cols via uint2.
__global__ __launch_bounds__(256) void k_agg2(const uint2* __restrict__ hwb, const int* __restrict__ esrc,
                                              const int* __restrict__ off, const int* __restrict__ deg,
                                              const float* __restrict__ dinv, const float* __restrict__ b,
                                              float* __restrict__ out, int N) {
    const int node = blockIdx.x * 4 + (threadIdx.x >> 6);
    if (node >= N) return;
    const int lane = threadIdx.x & 63;
    const int grp  = lane >> 4;          // 0..3
    const int lc   = lane & 15;          // uint2 index within row
    const int c0   = lc << 2;            // first of 4 cols

    const float di = dinv[node];
    float4 acc0 = {0,0,0,0}, acc1 = {0,0,0,0}, acc2 = {0,0,0,0}, acc3 = {0,0,0,0};
    if (grp == 0) {
        float w0 = di * di;
        uint2  sv = hwb[(size_t)node * 16 + lc];
        float4 bb = *(const float4*)&b[c0];
        acc0.x = bb.x + bf_lo(sv.x) * w0; acc0.y = bb.y + bf_hi(sv.x) * w0;
        acc0.z = bb.z + bf_lo(sv.y) * w0; acc0.w = bb.w + bf_hi(sv.y) * w0;
    }

    const int base = off[node];
    const int cnt  = deg[node] - 1;
    for (int p0 = 0; p0 < cnt; p0 += 64) {
        int   es = 0;
        float ew = 0.f;
        if (p0 + lane < cnt) {
            es = esrc[base + p0 + lane];
            ew = dinv[es] * di;
        }
        const int take = min(64, cnt - p0);
        int j = 0;
        for (; j + 16 <= take; j += 16) {
            int i0 = j + grp, i1 = j + 4 + grp, i2 = j + 8 + grp, i3 = j + 12 + grp;
            int   s0 = __shfl(es, i0); float w0f = __shfl(ew, i0);
            int   s1 = __shfl(es, i1); float w1f = __shfl(ew, i1);
            int   s2 = __shfl(es, i2); float w2f = __shfl(ew, i2);
            int   s3 = __shfl(es, i3); float w3f = __shfl(ew, i3);
            uint2 v0 = hwb[(size_t)s0 * 16 + lc];
            uint2 v1 = hwb[(size_t)s1 * 16 + lc];
            uint2 v2 = hwb[(size_t)s2 * 16 + lc];
            uint2 v3 = hwb[(size_t)s3 * 16 + lc];
            acc0.x += bf_lo(v0.x) * w0f; acc0.y += bf_hi(v0.x) * w0f;
            acc0.z += bf_lo(v0.y) * w0f; acc0.w += bf_hi(v0.y) * w0f;
            acc1.x += bf_lo(v1.x) * w1f; acc1.y += bf_hi(v1.x) * w1f;
            acc1.z += bf_lo(v1.y) * w1f; acc1.w += bf_hi(v1.y) * w1f;
            acc2.x += bf_lo(v2.x) * w2f; acc2.y += bf_hi(v2.x) * w2f;
            acc2.z += bf_lo(v2.y) * w2f; acc2.w += bf_hi(v2.y) * w2f;
            acc3.x += bf_lo(v3.x) * w3f; acc3.y += bf_hi(v3.x) * w3f;
            acc3.z += bf_lo(v3.y) * w3f; acc3.w += bf_hi(v3.y) * w3f;
        }
        for (; j < take; j += 4) {
            int i0 = j + grp;            // may hit a sentinel lane (w=0) — safe
            int   s0 = __shfl(es, i0); float w0f = __shfl(ew, i0);
            uint2 v0 = hwb[(size_t)s0 * 16 + lc];
            acc0.x += bf_lo(v0.x) * w0f; acc0.y += bf_hi(v0.x) * w0f;
            acc0.z += bf_lo(v0.y) * w0f; acc0.w += bf_hi(v0.y) * w0f;
        }
    }
    acc0.x += acc1.x + acc2.x + acc3.x;
    acc0.y += acc1.y + acc2.y + acc3.y;
    acc0.z += acc1.z + acc2.z + acc3.z;
    acc0.w += acc1.w + acc2.w + acc3.w;
    acc0.x += __shfl_xor(acc0.x, 16); acc0.y += __shfl_xor(acc0.y, 16);
    acc0.z += __shfl_xor(acc0.z, 16); acc0.w += __shfl_xor(acc0.w, 16);
    acc0.x += __shfl_xor(acc0.x, 32); acc0.y += __shfl_xor(acc0.y, 32);
    acc0.z += __shfl_xor(acc0.z, 32); acc0.w += __shfl_xor(acc0.w, 32);
    if (lane < 16) *(float4*)&out[(size_t)node * 64 + c0] = acc0;
}

extern "C" void kernel_launch(void* const* d_in, const int* in_sizes, int n_in,
                              void* d_out, int out_size, void* d_ws, size_t ws_size,
                              hipStream_t stream) {
    const float* x  = (const float*)d_in[0];
    const int*   ei = (const int*)  d_in[1];
    const float* W1 = (const float*)d_in[2];
    const float* b1 = (const float*)d_in[3];
    const float* W2 = (const float*)d_in[4];
    const float* b2 = (const float*)d_in[5];
    float* out = (float*)d_out;

    const int N = in_sizes[0] / 128;   // 50000
    const int E = in_sizes[1] / 2;     // 1600000
    const int* src = ei;
    const int* dst = ei + E;
    const int NB = (N + 255) / 256;    // scan blocks (196)

    // workspace layout:
    // deg[N] int | dinv[N] f32 | off[N] int | cursor[N] int | partial[256] int |
    // esrc[E] int | xwb[N*128] bf16 | out1[N*128] f32 | hwb[N*64] bf16
    char* w = (char*)d_ws;
    int*      deg     = (int*)w;              w += (size_t)N * 4;
    float*    dinv    = (float*)w;            w += (size_t)N * 4;
    int*      off     = (int*)w;              w += (size_t)N * 4;
    int*      cursor  = (int*)w;              w += (size_t)N * 4;
    int*      partial = (int*)w;              w += 256 * 4;
    int*      esrc    = (int*)w;              w += (size_t)E * 4;
    unsigned* xwb     = (unsigned*)w;         w += (size_t)N * 128 * 2;
    float*    out1    = (float*)w;            w += (size_t)N * 128 * 4;
    unsigned* hwb     = (unsigned*)w;

    // --- graph preprocessing (every call; deterministic workload) ---
    k_deg_init <<<NB, 256, 0, stream>>>(deg, N);
    k_deg_count<<<(E + 255) / 256, 256, 0, stream>>>(dst, deg, E);
    k_scan1    <<<NB, 256, 0, stream>>>(deg, dinv, off, partial, N);
    k_scan2    <<<1, 256, 0, stream>>>(partial, NB);
    k_scan3    <<<NB, 256, 0, stream>>>(off, partial, cursor, N);
    k_bucket   <<<(E + 255) / 256, 256, 0, stream>>>(src, dst, cursor, esrc, E);

    // --- layer 1 ---
    k_gemm1 <<<(N + 31) / 32, 256, 0, stream>>>(x, W1, xwb, N);
    k_agg1  <<<(N + 3) / 4, 256, 0, stream>>>((const uint2*)xwb, esrc, off, deg, dinv, b1, out1, N);

    // --- layer 2 ---
    k_gemm2 <<<(N + 31) / 32, 256, 0, stream>>>(out1, W2, hwb, N);
    k_agg2  <<<(N + 3) / 4, 256, 0, stream>>>((const uint2*)hwb, esrc, off, deg, dinv, b2, out, N);
}

// Round 6
// 371.441 us; speedup vs baseline: 1.0077x; 1.0077x over previous
//
#include <hip/hip_runtime.h>
#include <cstddef>

#define MAXB 512      // max coarse buckets (N<=65536 at 128 nodes/bucket)
#define CAPA 12       // LDS bin capacity (flush threshold 8)
#define CAPB 7936     // passB LDS staging entries (63.5 KB)
#define BSHIFT 7      // 128 dst nodes per bucket

// ---- bf16 pack/unpack helpers (RNE) ----
__device__ inline unsigned pack_bf16x2(float a, float b) {
    unsigned ua = __float_as_uint(a), ub = __float_as_uint(b);
    ua = (ua + 0x7FFFu + ((ua >> 16) & 1u)) >> 16;
    ub = (ub + 0x7FFFu + ((ub >> 16) & 1u)) >> 16;
    return ua | (ub << 16);
}
__device__ inline float bf_lo(unsigned u) { return __uint_as_float(u << 16); }
__device__ inline float bf_hi(unsigned u) { return __uint_as_float(u & 0xFFFF0000u); }

// ---------------- degree / norm ----------------
__global__ __launch_bounds__(256) void k_deg_init(int* __restrict__ deg, int n) {
    int i = blockIdx.x * 256 + threadIdx.x;
    if (i < n) deg[i] = 1;   // self-loop contributes 1
}

__global__ __launch_bounds__(256) void k_deg_count(const int* __restrict__ dst, int* __restrict__ deg, int e) {
    int i = blockIdx.x * 256 + threadIdx.x;
    if (i < e) atomicAdd(&deg[dst[i]], 1);
}

// ---------------- scan1: per-block exclusive scan of (deg-1); also emits dinv ----------------
__global__ __launch_bounds__(256) void k_scan1(const int* __restrict__ deg, float* __restrict__ dinv,
                                               int* __restrict__ off, int* __restrict__ partial, int N) {
    __shared__ int sh[256];
    int i = blockIdx.x * 256 + threadIdx.x;
    int d0 = (i < N) ? deg[i] : 1;
    if (i < N) dinv[i] = rsqrtf((float)d0);
    int v = (i < N) ? (d0 - 1) : 0;
    sh[threadIdx.x] = v;
    __syncthreads();
    for (int d = 1; d < 256; d <<= 1) {
        int t = (threadIdx.x >= d) ? sh[threadIdx.x - d] : 0;
        __syncthreads();
        sh[threadIdx.x] += t;
        __syncthreads();
    }
    if (i < N) off[i] = sh[threadIdx.x] - v;           // exclusive
    if (threadIdx.x == 255) partial[blockIdx.x] = sh[255];
}

__global__ __launch_bounds__(256) void k_scan2(int* __restrict__ partial, int nb) {
    __shared__ int sh[256];
    int v = (threadIdx.x < nb) ? partial[threadIdx.x] : 0;
    sh[threadIdx.x] = v;
    __syncthreads();
    for (int d = 1; d < 256; d <<= 1) {
        int t = (threadIdx.x >= d) ? sh[threadIdx.x - d] : 0;
        __syncthreads();
        sh[threadIdx.x] += t;
        __syncthreads();
    }
    if (threadIdx.x < nb) partial[threadIdx.x] = sh[threadIdx.x] - v;  // exclusive
}

__global__ __launch_bounds__(256) void k_scan3(int* __restrict__ off, const int* __restrict__ partial, int N) {
    int i = blockIdx.x * 256 + threadIdx.x;
    if (i < N) off[i] += partial[blockIdx.x];
}

// ---------------- bucket params: per-bucket start/count + padded scan ----------------
// single block, 512 threads; assumes nbuck <= 512 (N <= 65536)
__global__ __launch_bounds__(512) void k_bparam(const int* __restrict__ off, int* __restrict__ bstart,
                                                int* __restrict__ bcnt, int* __restrict__ pbase,
                                                int* __restrict__ bcur, int N, int E, int nbuck) {
    __shared__ int sh[512];
    const int b = threadIdx.x;
    int cnt = 0;
    if (b < nbuck) {
        int start = off[b << BSHIFT];
        int endi  = (b + 1) << BSHIFT;
        int end   = (endi >= N) ? E : off[endi];
        cnt = end - start;
        bstart[b] = start;
        bcnt[b]   = cnt;
    }
    int pad = (cnt + 7) & ~7;          // 8-entry (64B) aligned regions in tmp
    sh[b] = pad;
    __syncthreads();
    for (int d = 1; d < 512; d <<= 1) {
        int t = (b >= d) ? sh[b - d] : 0;
        __syncthreads();
        sh[b] += t;
        __syncthreads();
    }
    if (b < nbuck) { int p = sh[b] - pad; pbase[b] = p; bcur[b] = p; }
}

// ---------------- pass A: coarse split into buckets, full-line flushes ----------------
// tmp entries: {src, dst}. LDS bins accumulate 8-entry (64B) chunks per bucket.
__global__ __launch_bounds__(256) void k_passA(const int* __restrict__ src, const int* __restrict__ dst,
                                               int* __restrict__ bcur, int2* __restrict__ tmp,
                                               int E, int nbuck) {
    __shared__ __align__(16) int2 bins[MAXB * CAPA];
    __shared__ int cnt[MAXB];
    const int tid = threadIdx.x;
    for (int i = tid; i < nbuck; i += 256) cnt[i] = 0;
    __syncthreads();

    const int per = (E + gridDim.x - 1) / gridDim.x;
    const int e0  = blockIdx.x * per;
    const int e1  = min(e0 + per, E);

    for (int base = e0; base < e1; base += 256) {
        int e = base + tid;
        bool have = (e < e1);
        int2 ent = make_int2(0, 0);
        int  b = 0;
        if (have) { ent = make_int2(src[e], dst[e]); b = ent.y >> BSHIFT; }
        int pending = __syncthreads_count(have ? 1 : 0);
        while (pending) {
            if (have) {
                int slot = atomicAdd(&cnt[b], 1);
                if (slot < CAPA) { bins[b * CAPA + slot] = ent; have = false; }
            }
            __syncthreads();
            for (int bb = tid; bb < nbuck; bb += 256) {
                int real = min(cnt[bb], CAPA);
                int nf   = real & ~7;               // flush full 8-entry groups
                if (nf) {
                    int pos = atomicAdd(&bcur[bb], nf);
                    const int2* bp = &bins[bb * CAPA];
                    if ((pos & 1) == 0) {
                        for (int i = 0; i < nf; i += 2)
                            *(int4*)&tmp[pos + i] = *(const int4*)&bp[i];
                    } else {
                        for (int i = 0; i < nf; ++i) tmp[pos + i] = bp[i];
                    }
                    for (int i = nf; i < real; ++i)
                        bins[bb * CAPA + i - nf] = bins[bb * CAPA + i];
                }
                cnt[bb] = real - nf;
            }
            pending = __syncthreads_count(have ? 1 : 0);
        }
    }
    // final partial flush
    for (int bb = tid; bb < nbuck; bb += 256) {
        int real = cnt[bb];
        if (real) {
            int pos = atomicAdd(&bcur[bb], real);
            for (int i = 0; i < real; ++i) tmp[pos + i] = bins[bb * CAPA + i];
        }
    }
}

// ---------------- pass B: exact placement within bucket, coalesced dump ----------------
// reads tmp {src,dst}; writes epack {src, w=dinv[s]*dinv[d]} at off[dst] positions.
__global__ __launch_bounds__(256) void k_passB(const int2* __restrict__ tmp, const int* __restrict__ pbase,
                                               const int* __restrict__ bstart, const int* __restrict__ bcnt,
                                               const int* __restrict__ off, const float* __restrict__ dinv,
                                               int2* __restrict__ epack, int N) {
    __shared__ int  lcur[1 << BSHIFT];
    __shared__ int2 stag[CAPB];
    const int b     = blockIdx.x;
    const int tid   = threadIdx.x;
    const int node0 = b << BSHIFT;
    const int base  = bstart[b];
    const int cntB  = bcnt[b];
    const int pb    = pbase[b];
    if (tid < (1 << BSHIFT))
        lcur[tid] = (node0 + tid < N) ? (off[node0 + tid] - base) : 0;
    __syncthreads();
    const bool fits = (cntB <= CAPB);
    for (int i = tid; i < cntB; i += 256) {
        int2  ent = tmp[pb + i];
        float w   = dinv[ent.x] * dinv[ent.y];
        int   pos = atomicAdd(&lcur[ent.y - node0], 1);
        int2  ov  = make_int2(ent.x, __float_as_int(w));
        if (fits) stag[pos] = ov;
        else      epack[base + pos] = ov;   // safety fallback (rare)
    }
    __syncthreads();
    if (fits)
        for (int i = tid; i < cntB; i += 256) epack[base + i] = stag[i];
}

// ---------------- GEMM1: xwb[M,128](bf16) = x[M,128] @ W[128,128] ----------------
__global__ __launch_bounds__(256) void k_gemm1(const float* __restrict__ x, const float* __restrict__ W,
                                               unsigned* __restrict__ xwb, int M) {
    __shared__ float ws[128 * 128];      // ws[k*128 + c]
    __shared__ float xs[128][32];        // xs[k][r]  (transposed tile)
    const int tid  = threadIdx.x;
    const int row0 = blockIdx.x * 32;

    for (int i = tid * 4; i < 128 * 128; i += 1024)
        *(float4*)&ws[i] = *(const float4*)&W[i];

    for (int i = tid; i < 32 * 32; i += 256) {
        int r  = i >> 5;
        int cc = (i & 31) << 2;
        float4 v = make_float4(0.f, 0.f, 0.f, 0.f);
        if (row0 + r < M) v = *(const float4*)&x[(size_t)(row0 + r) * 128 + cc];
        xs[cc + 0][r] = v.x; xs[cc + 1][r] = v.y; xs[cc + 2][r] = v.z; xs[cc + 3][r] = v.w;
    }
    __syncthreads();

    const int c0 = (tid & 31) << 2;      // 4 cols
    const int r0 = (tid >> 5) << 2;      // 4 rows
    float4 a0 = {0,0,0,0}, a1 = {0,0,0,0}, a2 = {0,0,0,0}, a3 = {0,0,0,0};
#pragma unroll 8
    for (int k = 0; k < 128; ++k) {
        float4 wv = *(const float4*)&ws[k * 128 + c0];
        float4 xv = *(const float4*)&xs[k][r0];
        a0.x += xv.x * wv.x; a0.y += xv.x * wv.y; a0.z += xv.x * wv.z; a0.w += xv.x * wv.w;
        a1.x += xv.y * wv.x; a1.y += xv.y * wv.y; a1.z += xv.y * wv.z; a1.w += xv.y * wv.w;
        a2.x += xv.z * wv.x; a2.y += xv.z * wv.y; a2.z += xv.z * wv.z; a2.w += xv.z * wv.w;
        a3.x += xv.w * wv.x; a3.y += xv.w * wv.y; a3.z += xv.w * wv.z; a3.w += xv.w * wv.w;
    }
    uint2* o = (uint2*)xwb;
    if (row0 + r0 + 0 < M) o[(size_t)(row0 + r0 + 0) * 32 + (c0 >> 2)] = make_uint2(pack_bf16x2(a0.x, a0.y), pack_bf16x2(a0.z, a0.w));
    if (row0 + r0 + 1 < M) o[(size_t)(row0 + r0 + 1) * 32 + (c0 >> 2)] = make_uint2(pack_bf16x2(a1.x, a1.y), pack_bf16x2(a1.z, a1.w));
    if (row0 + r0 + 2 < M) o[(size_t)(row0 + r0 + 2) * 32 + (c0 >> 2)] = make_uint2(pack_bf16x2(a2.x, a2.y), pack_bf16x2(a2.z, a2.w));
    if (row0 + r0 + 3 < M) o[(size_t)(row0 + r0 + 3) * 32 + (c0 >> 2)] = make_uint2(pack_bf16x2(a3.x, a3.y), pack_bf16x2(a3.z, a3.w));
}

// ---------------- GEMM2: hwb[M,64](bf16) = relu(h[M,128]) @ W[128,64] ----------------
__global__ __launch_bounds__(256) void k_gemm2(const float* __restrict__ h_in, const float* __restrict__ W,
                                               unsigned* __restrict__ hwb, int M) {
    __shared__ float ws[128 * 64];       // ws[k*64 + c]
    __shared__ float xs[128][32];        // xs[k][r]
    const int tid  = threadIdx.x;
    const int row0 = blockIdx.x * 32;

    for (int i = tid * 4; i < 128 * 64; i += 1024)
        *(float4*)&ws[i] = *(const float4*)&W[i];

    for (int i = tid; i < 32 * 32; i += 256) {
        int r  = i >> 5;
        int cc = (i & 31) << 2;
        float4 v = make_float4(0.f, 0.f, 0.f, 0.f);
        if (row0 + r < M) {
            v = *(const float4*)&h_in[(size_t)(row0 + r) * 128 + cc];
            v.x = fmaxf(v.x, 0.f); v.y = fmaxf(v.y, 0.f);
            v.z = fmaxf(v.z, 0.f); v.w = fmaxf(v.w, 0.f);
        }
        xs[cc + 0][r] = v.x; xs[cc + 1][r] = v.y; xs[cc + 2][r] = v.z; xs[cc + 3][r] = v.w;
    }
    __syncthreads();

    const int c0 = (tid & 15) << 2;      // 4 cols of 64
    const int r0 = (tid >> 4) << 1;      // 2 rows
    float4 a0 = {0,0,0,0}, a1 = {0,0,0,0};
#pragma unroll 8
    for (int k = 0; k < 128; ++k) {
        float4 wv = *(const float4*)&ws[k * 64 + c0];
        float2 xv = *(const float2*)&xs[k][r0];
        a0.x += xv.x * wv.x; a0.y += xv.x * wv.y; a0.z += xv.x * wv.z; a0.w += xv.x * wv.w;
        a1.x += xv.y * wv.x; a1.y += xv.y * wv.y; a1.z += xv.y * wv.z; a1.w += xv.y * wv.w;
    }
    uint2* o = (uint2*)hwb;
    if (row0 + r0 + 0 < M) o[(size_t)(row0 + r0 + 0) * 16 + (c0 >> 2)] = make_uint2(pack_bf16x2(a0.x, a0.y), pack_bf16x2(a0.z, a0.w));
    if (row0 + r0 + 1 < M) o[(size_t)(row0 + r0 + 1) * 16 + (c0 >> 2)] = make_uint2(pack_bf16x2(a1.x, a1.y), pack_bf16x2(a1.z, a1.w));
}

// ---------------- pull aggregation, layer1 (bf16 gather) ----------------
__global__ __launch_bounds__(256) void k_agg1(const uint2* __restrict__ xwb, const int2* __restrict__ epack,
                                              const int* __restrict__ off, const int* __restrict__ deg,
                                              const float* __restrict__ dinv, const float* __restrict__ b,
                                              float* __restrict__ out1, int N) {
    const int node = blockIdx.x * 4 + (threadIdx.x >> 6);
    if (node >= N) return;
    const int lane = threadIdx.x & 63;
    const int half = lane >> 5;          // 0 or 1
    const int lc   = lane & 31;          // uint2 index within row
    const int c0   = lc << 2;            // first of 4 cols

    float4 acc0 = {0,0,0,0}, acc1 = {0,0,0,0}, acc2 = {0,0,0,0}, acc3 = {0,0,0,0};
    if (half == 0) {                     // self-loop + bias on half 0 only
        float di = dinv[node];
        float w0 = di * di;
        uint2  sv = xwb[(size_t)node * 32 + lc];
        float4 bb = *(const float4*)&b[c0];
        acc0.x = bb.x + bf_lo(sv.x) * w0; acc0.y = bb.y + bf_hi(sv.x) * w0;
        acc0.z = bb.z + bf_lo(sv.y) * w0; acc0.w = bb.w + bf_hi(sv.y) * w0;
    }

    const int base = off[node];
    const int cnt  = deg[node] - 1;      // real (non-self) in-edges
    for (int p0 = 0; p0 < cnt; p0 += 64) {
        int2 ep = make_int2(0, 0);       // w=0 sentinel: gathers row 0, adds 0
        if (p0 + lane < cnt) ep = epack[base + p0 + lane];
        const int take = min(64, cnt - p0);
        int j = 0;
        for (; j + 8 <= take; j += 8) {
            int i0 = j + half, i1 = j + 2 + half, i2 = j + 4 + half, i3 = j + 6 + half;
            int   s0 = __shfl(ep.x, i0); float w0f = __int_as_float(__shfl(ep.y, i0));
            int   s1 = __shfl(ep.x, i1); float w1f = __int_as_float(__shfl(ep.y, i1));
            int   s2 = __shfl(ep.x, i2); float w2f = __int_as_float(__shfl(ep.y, i2));
            int   s3 = __shfl(ep.x, i3); float w3f = __int_as_float(__shfl(ep.y, i3));
            uint2 v0 = xwb[(size_t)s0 * 32 + lc];
            uint2 v1 = xwb[(size_t)s1 * 32 + lc];
            uint2 v2 = xwb[(size_t)s2 * 32 + lc];
            uint2 v3 = xwb[(size_t)s3 * 32 + lc];
            acc0.x += bf_lo(v0.x) * w0f; acc0.y += bf_hi(v0.x) * w0f;
            acc0.z += bf_lo(v0.y) * w0f; acc0.w += bf_hi(v0.y) * w0f;
            acc1.x += bf_lo(v1.x) * w1f; acc1.y += bf_hi(v1.x) * w1f;
            acc1.z += bf_lo(v1.y) * w1f; acc1.w += bf_hi(v1.y) * w1f;
            acc2.x += bf_lo(v2.x) * w2f; acc2.y += bf_hi(v2.x) * w2f;
            acc2.z += bf_lo(v2.y) * w2f; acc2.w += bf_hi(v2.y) * w2f;
            acc3.x += bf_lo(v3.x) * w3f; acc3.y += bf_hi(v3.x) * w3f;
            acc3.z += bf_lo(v3.y) * w3f; acc3.w += bf_hi(v3.y) * w3f;
        }
        for (; j < take; j += 2) {
            int i0 = j + half;           // may hit a sentinel lane (w=0) — safe
            int   s0 = __shfl(ep.x, i0); float w0f = __int_as_float(__shfl(ep.y, i0));
            uint2 v0 = xwb[(size_t)s0 * 32 + lc];
            acc0.x += bf_lo(v0.x) * w0f; acc0.y += bf_hi(v0.x) * w0f;
            acc0.z += bf_lo(v0.y) * w0f; acc0.w += bf_hi(v0.y) * w0f;
        }
    }
    acc0.x += acc1.x + acc2.x + acc3.x;
    acc0.y += acc1.y + acc2.y + acc3.y;
    acc0.z += acc1.z + acc2.z + acc3.z;
    acc0.w += acc1.w + acc2.w + acc3.w;
    acc0.x += __shfl_xor(acc0.x, 32);
    acc0.y += __shfl_xor(acc0.y, 32);
    acc0.z += __shfl_xor(acc0.z, 32);
    acc0.w += __shfl_xor(acc0.w, 32);
    if (half == 0) *(float4*)&out1[(size_t)node * 128 + c0] = acc0;
}

// ---------------- pull aggregation, layer2 (bf16 gather) ----------------
__global__ __launch_bounds__(256) void k_agg2(const uint2* __restrict__ hwb, const int2* __restrict__ epack,
                                              const int* __restrict__ off, const int* __restrict__ deg,
                                              const float* __restrict__ dinv, const float* __restrict__ b,
                                              float* __restrict__ out, int N) {
    const int node = blockIdx.x * 4 + (threadIdx.x >> 6);
    if (node >= N) return;
    const int lane = threadIdx.x & 63;
    const int grp  = lane >> 4;          // 0..3
    const int lc   = lane & 15;          // uint2 index within row
    const int c0   = lc << 2;            // first of 4 cols

    float4 acc0 = {0,0,0,0}, acc1 = {0,0,0,0}, acc2 = {0,0,0,0}, acc3 = {0,0,0,0};
    if (grp == 0) {
        float di = dinv[node];
        float w0 = di * di;
        uint2  sv = hwb[(size_t)node * 16 + lc];
        float4 bb = *(const float4*)&b[c0];
        acc0.x = bb.x + bf_lo(sv.x) * w0; acc0.y = bb.y + bf_hi(sv.x) * w0;
        acc0.z = bb.z + bf_lo(sv.y) * w0; acc0.w = bb.w + bf_hi(sv.y) * w0;
    }

    const int base = off[node];
    const int cnt  = deg[node] - 1;
    for (int p0 = 0; p0 < cnt; p0 += 64) {
        int2 ep = make_int2(0, 0);
        if (p0 + lane < cnt) ep = epack[base + p0 + lane];
        const int take = min(64, cnt - p0);
        int j = 0;
        for (; j + 16 <= take; j += 16) {
            int i0 = j + grp, i1 = j + 4 + grp, i2 = j + 8 + grp, i3 = j + 12 + grp;
            int   s0 = __shfl(ep.x, i0); float w0f = __int_as_float(__shfl(ep.y, i0));
            int   s1 = __shfl(ep.x, i1); float w1f = __int_as_float(__shfl(ep.y, i1));
            int   s2 = __shfl(ep.x, i2); float w2f = __int_as_float(__shfl(ep.y, i2));
            int   s3 = __shfl(ep.x, i3); float w3f = __int_as_float(__shfl(ep.y, i3));
            uint2 v0 = hwb[(size_t)s0 * 16 + lc];
            uint2 v1 = hwb[(size_t)s1 * 16 + lc];
            uint2 v2 = hwb[(size_t)s2 * 16 + lc];
            uint2 v3 = hwb[(size_t)s3 * 16 + lc];
            acc0.x += bf_lo(v0.x) * w0f; acc0.y += bf_hi(v0.x) * w0f;
            acc0.z += bf_lo(v0.y) * w0f; acc0.w += bf_hi(v0.y) * w0f;
            acc1.x += bf_lo(v1.x) * w1f; acc1.y += bf_hi(v1.x) * w1f;
            acc1.z += bf_lo(v1.y) * w1f; acc1.w += bf_hi(v1.y) * w1f;
            acc2.x += bf_lo(v2.x) * w2f; acc2.y += bf_hi(v2.x) * w2f;
            acc2.z += bf_lo(v2.y) * w2f; acc2.w += bf_hi(v2.y) * w2f;
            acc3.x += bf_lo(v3.x) * w3f; acc3.y += bf_hi(v3.x) * w3f;
            acc3.z += bf_lo(v3.y) * w3f; acc3.w += bf_hi(v3.y) * w3f;
        }
        for (; j < take; j += 4) {
            int i0 = j + grp;            // may hit a sentinel lane (w=0) — safe
            int   s0 = __shfl(ep.x, i0); float w0f = __int_as_float(__shfl(ep.y, i0));
            uint2 v0 = hwb[(size_t)s0 * 16 + lc];
            acc0.x += bf_lo(v0.x) * w0f; acc0.y += bf_hi(v0.x) * w0f;
            acc0.z += bf_lo(v0.y) * w0f; acc0.w += bf_hi(v0.y) * w0f;
        }
    }
    acc0.x += acc1.x + acc2.x + acc3.x;
    acc0.y += acc1.y + acc2.y + acc3.y;
    acc0.z += acc1.z + acc2.z + acc3.z;
    acc0.w += acc1.w + acc2.w + acc3.w;
    acc0.x += __shfl_xor(acc0.x, 16); acc0.y += __shfl_xor(acc0.y, 16);
    acc0.z += __shfl_xor(acc0.z, 16); acc0.w += __shfl_xor(acc0.w, 16);
    acc0.x += __shfl_xor(acc0.x, 32); acc0.y += __shfl_xor(acc0.y, 32);
    acc0.z += __shfl_xor(acc0.z, 32); acc0.w += __shfl_xor(acc0.w, 32);
    if (lane < 16) *(float4*)&out[(size_t)node * 64 + c0] = acc0;
}

extern "C" void kernel_launch(void* const* d_in, const int* in_sizes, int n_in,
                              void* d_out, int out_size, void* d_ws, size_t ws_size,
                              hipStream_t stream) {
    const float* x  = (const float*)d_in[0];
    const int*   ei = (const int*)  d_in[1];
    const float* W1 = (const float*)d_in[2];
    const float* b1 = (const float*)d_in[3];
    const float* W2 = (const float*)d_in[4];
    const float* b2 = (const float*)d_in[5];
    float* out = (float*)d_out;

    const int N = in_sizes[0] / 128;   // 50000
    const int E = in_sizes[1] / 2;     // 1600000
    const int* src = ei;
    const int* dst = ei + E;
    const int NB    = (N + 255) / 256;        // scan blocks (196)
    const int NBUCK = (N + 127) / 128;        // 391 (assumes <= 512)

    // workspace layout:
    // deg[N] | dinv[N] | off[N] | partial[256] | bstart[512] | bcnt[512] | pbase[512] | bcur[512]
    // | epack[E] int2 | xwb[N*128] bf16 | out1[N*128] f32 (aliases tmp[E+pad] int2) | hwb[N*64] bf16
    char* w = (char*)d_ws;
    int*      deg     = (int*)w;              w += (size_t)N * 4;
    float*    dinv    = (float*)w;            w += (size_t)N * 4;
    int*      off     = (int*)w;              w += (size_t)N * 4;
    int*      partial = (int*)w;              w += 256 * 4;
    int*      bstart  = (int*)w;              w += 512 * 4;
    int*      bcnt    = (int*)w;              w += 512 * 4;
    int*      pbase   = (int*)w;              w += 512 * 4;
    int*      bcur    = (int*)w;              w += 512 * 4;
    int2*     epack   = (int2*)w;             w += (size_t)E * 8;
    unsigned* xwb     = (unsigned*)w;         w += (size_t)N * 128 * 2;
    float*    out1    = (float*)w;            w += (size_t)N * 128 * 4;
    unsigned* hwb     = (unsigned*)w;
    int2*     tmp     = (int2*)out1;          // tmp dead before agg1 writes out1

    // --- graph preprocessing (every call; deterministic workload) ---
    k_deg_init <<<NB, 256, 0, stream>>>(deg, N);
    k_deg_count<<<(E + 255) / 256, 256, 0, stream>>>(dst, deg, E);
    k_scan1    <<<NB, 256, 0, stream>>>(deg, dinv, off, partial, N);
    k_scan2    <<<1, 256, 0, stream>>>(partial, NB);
    k_scan3    <<<NB, 256, 0, stream>>>(off, partial, N);
    k_bparam   <<<1, 512, 0, stream>>>(off, bstart, bcnt, pbase, bcur, N, E, NBUCK);
    k_passA    <<<256, 256, 0, stream>>>(src, dst, bcur, tmp, E, NBUCK);
    k_passB    <<<NBUCK, 256, 0, stream>>>(tmp, pbase, bstart, bcnt, off, dinv, epack, N);

    // --- layer 1 ---
    k_gemm1 <<<(N + 31) / 32, 256, 0, stream>>>(x, W1, xwb, N);
    k_agg1  <<<(N + 3) / 4, 256, 0, stream>>>((const uint2*)xwb, epack, off, deg, dinv, b1, out1, N);

    // --- layer 2 ---
    k_gemm2 <<<(N + 31) / 32, 256, 0, stream>>>(out1, W2, hwb, N);
    k_agg2  <<<(N + 3) / 4, 256, 0, stream>>>((const uint2*)hwb, epack, off, deg, dinv, b2, out, N);
}

// Round 7
// 316.294 us; speedup vs baseline: 1.1833x; 1.1744x over previous
//
#include <hip/hip_runtime.h>
#include <cstddef>

#define MAXB 512      // max coarse buckets (N<=65536 at 128 nodes/bucket)
#define BSHIFT 7      // 128 dst nodes per bucket
#define ACHUNK 8192   // edges per passA block

// ---- bf16 pack/unpack helpers (RNE) ----
__device__ inline unsigned pack_bf16x2(float a, float b) {
    unsigned ua = __float_as_uint(a), ub = __float_as_uint(b);
    ua = (ua + 0x7FFFu + ((ua >> 16) & 1u)) >> 16;
    ub = (ub + 0x7FFFu + ((ub >> 16) & 1u)) >> 16;
    return ua | (ub << 16);
}
__device__ inline float bf_lo(unsigned u) { return __uint_as_float(u << 16); }
__device__ inline float bf_hi(unsigned u) { return __uint_as_float(u & 0xFFFF0000u); }

// ---------------- degree / norm ----------------
__global__ __launch_bounds__(256) void k_deg_init(int* __restrict__ deg, int n) {
    int i = blockIdx.x * 256 + threadIdx.x;
    if (i < n) deg[i] = 1;   // self-loop contributes 1
}

__global__ __launch_bounds__(256) void k_deg_count(const int* __restrict__ dst, int* __restrict__ deg, int e) {
    int i = blockIdx.x * 256 + threadIdx.x;
    if (i < e) atomicAdd(&deg[dst[i]], 1);
}

// ---------------- scan1: per-block exclusive scan of (deg-1); also emits dinv ----------------
__global__ __launch_bounds__(256) void k_scan1(const int* __restrict__ deg, float* __restrict__ dinv,
                                               int* __restrict__ off, int* __restrict__ partial, int N) {
    __shared__ int sh[256];
    int i = blockIdx.x * 256 + threadIdx.x;
    int d0 = (i < N) ? deg[i] : 1;
    if (i < N) dinv[i] = rsqrtf((float)d0);
    int v = (i < N) ? (d0 - 1) : 0;
    sh[threadIdx.x] = v;
    __syncthreads();
    for (int d = 1; d < 256; d <<= 1) {
        int t = (threadIdx.x >= d) ? sh[threadIdx.x - d] : 0;
        __syncthreads();
        sh[threadIdx.x] += t;
        __syncthreads();
    }
    if (i < N) off[i] = sh[threadIdx.x] - v;           // exclusive
    if (threadIdx.x == 255) partial[blockIdx.x] = sh[255];
}

__global__ __launch_bounds__(256) void k_scan2(int* __restrict__ partial, int nb) {
    __shared__ int sh[256];
    int v = (threadIdx.x < nb) ? partial[threadIdx.x] : 0;
    sh[threadIdx.x] = v;
    __syncthreads();
    for (int d = 1; d < 256; d <<= 1) {
        int t = (threadIdx.x >= d) ? sh[threadIdx.x - d] : 0;
        __syncthreads();
        sh[threadIdx.x] += t;
        __syncthreads();
    }
    if (threadIdx.x < nb) partial[threadIdx.x] = sh[threadIdx.x] - v;  // exclusive
}

__global__ __launch_bounds__(256) void k_scan3(int* __restrict__ off, const int* __restrict__ partial, int N) {
    int i = blockIdx.x * 256 + threadIdx.x;
    if (i < N) off[i] += partial[blockIdx.x];
}

// ---------------- bucket params ----------------
__global__ __launch_bounds__(256) void k_bparam(const int* __restrict__ off, int* __restrict__ bstart,
                                                int* __restrict__ bcnt, int* __restrict__ bcur,
                                                int N, int E, int nbuck) {
    int b = blockIdx.x * 256 + threadIdx.x;
    if (b < nbuck) {
        int start = off[b << BSHIFT];
        int endi  = (b + 1) << BSHIFT;
        int end   = (endi >= N) ? E : off[endi];
        bstart[b] = start;
        bcnt[b]   = end - start;
        bcur[b]   = start;
    }
}

// ---------------- pass A: coarse split into bucket runs (block-owned reservations) ----------------
// tmp entries: {src, dst}. Per-block histogram -> one batched cursor reservation per
// bucket -> scatter. Each bucket run is block-owned, so cache lines are written from
// one XCD and evicted once (no cross-XCD partial-line amplification).
__global__ __launch_bounds__(256) void k_passA(const int* __restrict__ src, const int* __restrict__ dst,
                                               int* __restrict__ bcur, int2* __restrict__ tmp,
                                               int E, int nbuck) {
    __shared__ int hist[MAXB];
    __shared__ int gbase[MAXB];
    const int tid = threadIdx.x;
    const int e0  = blockIdx.x * ACHUNK;
    const int e1  = min(e0 + ACHUNK, E);
    for (int i = tid; i < nbuck; i += 256) hist[i] = 0;
    __syncthreads();
    for (int e = e0 + tid; e < e1; e += 256)
        atomicAdd(&hist[dst[e] >> BSHIFT], 1);
    __syncthreads();
    for (int i = tid; i < nbuck; i += 256) {
        int c = hist[i];
        gbase[i] = c ? atomicAdd(&bcur[i], c) : 0;
        hist[i] = 0;                       // reuse as local cursor
    }
    __syncthreads();
    for (int e = e0 + tid; e < e1; e += 256) {
        int d = dst[e];
        int b = d >> BSHIFT;
        int slot = atomicAdd(&hist[b], 1);
        tmp[gbase[b] + slot] = make_int2(src[e], d);
    }
}

// ---------------- pass B: exact placement within bucket ----------------
// All writes to epack[bstart..bstart+bcnt) come from this block (one XCD L2),
// so direct random writes within the 32KB region cost ~1x on eviction.
__global__ __launch_bounds__(256) void k_passB(const int2* __restrict__ tmp, const int* __restrict__ bstart,
                                               const int* __restrict__ bcnt, const int* __restrict__ off,
                                               const float* __restrict__ dinv, int2* __restrict__ epack, int N) {
    __shared__ int lcur[1 << BSHIFT];
    const int b     = blockIdx.x;
    const int tid   = threadIdx.x;
    const int node0 = b << BSHIFT;
    const int base  = bstart[b];
    const int cntB  = bcnt[b];
    if (tid < (1 << BSHIFT))
        lcur[tid] = (node0 + tid < N) ? (off[node0 + tid] - base) : 0;
    __syncthreads();
    for (int i = tid; i < cntB; i += 256) {
        int2  ent = tmp[base + i];
        float w   = dinv[ent.x] * dinv[ent.y];
        int   pos = atomicAdd(&lcur[ent.y - node0], 1);
        epack[base + pos] = make_int2(ent.x, __float_as_int(w));
    }
}

// ---------------- GEMM1: xwb[M,128](bf16) = x[M,128] @ W[128,128] ----------------
__global__ __launch_bounds__(256) void k_gemm1(const float* __restrict__ x, const float* __restrict__ W,
                                               unsigned* __restrict__ xwb, int M) {
    __shared__ float ws[128 * 128];      // ws[k*128 + c]
    __shared__ float xs[128][32];        // xs[k][r]  (transposed tile)
    const int tid  = threadIdx.x;
    const int row0 = blockIdx.x * 32;

    for (int i = tid * 4; i < 128 * 128; i += 1024)
        *(float4*)&ws[i] = *(const float4*)&W[i];

    for (int i = tid; i < 32 * 32; i += 256) {
        int r  = i >> 5;
        int cc = (i & 31) << 2;
        float4 v = make_float4(0.f, 0.f, 0.f, 0.f);
        if (row0 + r < M) v = *(const float4*)&x[(size_t)(row0 + r) * 128 + cc];
        xs[cc + 0][r] = v.x; xs[cc + 1][r] = v.y; xs[cc + 2][r] = v.z; xs[cc + 3][r] = v.w;
    }
    __syncthreads();

    const int c0 = (tid & 31) << 2;      // 4 cols
    const int r0 = (tid >> 5) << 2;      // 4 rows
    float4 a0 = {0,0,0,0}, a1 = {0,0,0,0}, a2 = {0,0,0,0}, a3 = {0,0,0,0};
#pragma unroll 8
    for (int k = 0; k < 128; ++k) {
        float4 wv = *(const float4*)&ws[k * 128 + c0];
        float4 xv = *(const float4*)&xs[k][r0];
        a0.x += xv.x * wv.x; a0.y += xv.x * wv.y; a0.z += xv.x * wv.z; a0.w += xv.x * wv.w;
        a1.x += xv.y * wv.x; a1.y += xv.y * wv.y; a1.z += xv.y * wv.z; a1.w += xv.y * wv.w;
        a2.x += xv.z * wv.x; a2.y += xv.z * wv.y; a2.z += xv.z * wv.z; a2.w += xv.z * wv.w;
        a3.x += xv.w * wv.x; a3.y += xv.w * wv.y; a3.z += xv.w * wv.z; a3.w += xv.w * wv.w;
    }
    uint2* o = (uint2*)xwb;
    if (row0 + r0 + 0 < M) o[(size_t)(row0 + r0 + 0) * 32 + (c0 >> 2)] = make_uint2(pack_bf16x2(a0.x, a0.y), pack_bf16x2(a0.z, a0.w));
    if (row0 + r0 + 1 < M) o[(size_t)(row0 + r0 + 1) * 32 + (c0 >> 2)] = make_uint2(pack_bf16x2(a1.x, a1.y), pack_bf16x2(a1.z, a1.w));
    if (row0 + r0 + 2 < M) o[(size_t)(row0 + r0 + 2) * 32 + (c0 >> 2)] = make_uint2(pack_bf16x2(a2.x, a2.y), pack_bf16x2(a2.z, a2.w));
    if (row0 + r0 + 3 < M) o[(size_t)(row0 + r0 + 3) * 32 + (c0 >> 2)] = make_uint2(pack_bf16x2(a3.x, a3.y), pack_bf16x2(a3.z, a3.w));
}

// ---------------- GEMM2: hwb[M,64](bf16) = relu(h[M,128]) @ W[128,64] ----------------
__global__ __launch_bounds__(256) void k_gemm2(const float* __restrict__ h_in, const float* __restrict__ W,
                                               unsigned* __restrict__ hwb, int M) {
    __shared__ float ws[128 * 64];       // ws[k*64 + c]
    __shared__ float xs[128][32];        // xs[k][r]
    const int tid  = threadIdx.x;
    const int row0 = blockIdx.x * 32;

    for (int i = tid * 4; i < 128 * 64; i += 1024)
        *(float4*)&ws[i] = *(const float4*)&W[i];

    for (int i = tid; i < 32 * 32; i += 256) {
        int r  = i >> 5;
        int cc = (i & 31) << 2;
        float4 v = make_float4(0.f, 0.f, 0.f, 0.f);
        if (row0 + r < M) {
            v = *(const float4*)&h_in[(size_t)(row0 + r) * 128 + cc];
            v.x = fmaxf(v.x, 0.f); v.y = fmaxf(v.y, 0.f);
            v.z = fmaxf(v.z, 0.f); v.w = fmaxf(v.w, 0.f);
        }
        xs[cc + 0][r] = v.x; xs[cc + 1][r] = v.y; xs[cc + 2][r] = v.z; xs[cc + 3][r] = v.w;
    }
    __syncthreads();

    const int c0 = (tid & 15) << 2;      // 4 cols of 64
    const int r0 = (tid >> 4) << 1;      // 2 rows
    float4 a0 = {0,0,0,0}, a1 = {0,0,0,0};
#pragma unroll 8
    for (int k = 0; k < 128; ++k) {
        float4 wv = *(const float4*)&ws[k * 64 + c0];
        float2 xv = *(const float2*)&xs[k][r0];
        a0.x += xv.x * wv.x; a0.y += xv.x * wv.y; a0.z += xv.x * wv.z; a0.w += xv.x * wv.w;
        a1.x += xv.y * wv.x; a1.y += xv.y * wv.y; a1.z += xv.y * wv.z; a1.w += xv.y * wv.w;
    }
    uint2* o = (uint2*)hwb;
    if (row0 + r0 + 0 < M) o[(size_t)(row0 + r0 + 0) * 16 + (c0 >> 2)] = make_uint2(pack_bf16x2(a0.x, a0.y), pack_bf16x2(a0.z, a0.w));
    if (row0 + r0 + 1 < M) o[(size_t)(row0 + r0 + 1) * 16 + (c0 >> 2)] = make_uint2(pack_bf16x2(a1.x, a1.y), pack_bf16x2(a1.z, a1.w));
}

// ---------------- pull aggregation, layer1 (bf16 gather) ----------------
__global__ __launch_bounds__(256) void k_agg1(const uint2* __restrict__ xwb, const int2* __restrict__ epack,
                                              const int* __restrict__ off, const int* __restrict__ deg,
                                              const float* __restrict__ dinv, const float* __restrict__ b,
                                              float* __restrict__ out1, int N) {
    const int node = blockIdx.x * 4 + (threadIdx.x >> 6);
    if (node >= N) return;
    const int lane = threadIdx.x & 63;
    const int half = lane >> 5;          // 0 or 1
    const int lc   = lane & 31;          // uint2 index within row
    const int c0   = lc << 2;            // first of 4 cols

    float4 acc0 = {0,0,0,0}, acc1 = {0,0,0,0}, acc2 = {0,0,0,0}, acc3 = {0,0,0,0};
    if (half == 0) {                     // self-loop + bias on half 0 only
        float di = dinv[node];
        float w0 = di * di;
        uint2  sv = xwb[(size_t)node * 32 + lc];
        float4 bb = *(const float4*)&b[c0];
        acc0.x = bb.x + bf_lo(sv.x) * w0; acc0.y = bb.y + bf_hi(sv.x) * w0;
        acc0.z = bb.z + bf_lo(sv.y) * w0; acc0.w = bb.w + bf_hi(sv.y) * w0;
    }

    const int base = off[node];
    const int cnt  = deg[node] - 1;      // real (non-self) in-edges
    for (int p0 = 0; p0 < cnt; p0 += 64) {
        int2 ep = make_int2(0, 0);       // w=0 sentinel: gathers row 0, adds 0
        if (p0 + lane < cnt) ep = epack[base + p0 + lane];
        const int take = min(64, cnt - p0);
        int j = 0;
        for (; j + 8 <= take; j += 8) {
            int i0 = j + half, i1 = j + 2 + half, i2 = j + 4 + half, i3 = j + 6 + half;
            int   s0 = __shfl(ep.x, i0); float w0f = __int_as_float(__shfl(ep.y, i0));
            int   s1 = __shfl(ep.x, i1); float w1f = __int_as_float(__shfl(ep.y, i1));
            int   s2 = __shfl(ep.x, i2); float w2f = __int_as_float(__shfl(ep.y, i2));
            int   s3 = __shfl(ep.x, i3); float w3f = __int_as_float(__shfl(ep.y, i3));
            uint2 v0 = xwb[(size_t)s0 * 32 + lc];
            uint2 v1 = xwb[(size_t)s1 * 32 + lc];
            uint2 v2 = xwb[(size_t)s2 * 32 + lc];
            uint2 v3 = xwb[(size_t)s3 * 32 + lc];
            acc0.x += bf_lo(v0.x) * w0f; acc0.y += bf_hi(v0.x) * w0f;
            acc0.z += bf_lo(v0.y) * w0f; acc0.w += bf_hi(v0.y) * w0f;
            acc1.x += bf_lo(v1.x) * w1f; acc1.y += bf_hi(v1.x) * w1f;
            acc1.z += bf_lo(v1.y) * w1f; acc1.w += bf_hi(v1.y) * w1f;
            acc2.x += bf_lo(v2.x) * w2f; acc2.y += bf_hi(v2.x) * w2f;
            acc2.z += bf_lo(v2.y) * w2f; acc2.w += bf_hi(v2.y) * w2f;
            acc3.x += bf_lo(v3.x) * w3f; acc3.y += bf_hi(v3.x) * w3f;
            acc3.z += bf_lo(v3.y) * w3f; acc3.w += bf_hi(v3.y) * w3f;
        }
        for (; j < take; j += 2) {
            int i0 = j + half;           // may hit a sentinel lane (w=0) — safe
            int   s0 = __shfl(ep.x, i0); float w0f = __int_as_float(__shfl(ep.y, i0));
            uint2 v0 = xwb[(size_t)s0 * 32 + lc];
            acc0.x += bf_lo(v0.x) * w0f; acc0.y += bf_hi(v0.x) * w0f;
            acc0.z += bf_lo(v0.y) * w0f; acc0.w += bf_hi(v0.y) * w0f;
        }
    }
    acc0.x += acc1.x + acc2.x + acc3.x;
    acc0.y += acc1.y + acc2.y + acc3.y;
    acc0.z += acc1.z + acc2.z + acc3.z;
    acc0.w += acc1.w + acc2.w + acc3.w;
    acc0.x += __shfl_xor(acc0.x, 32);
    acc0.y += __shfl_xor(acc0.y, 32);
    acc0.z += __shfl_xor(acc0.z, 32);
    acc0.w += __shfl_xor(acc0.w, 32);
    if (half == 0) *(float4*)&out1[(size_t)node * 128 + c0] = acc0;
}

// ---------------- pull aggregation, layer2 (bf16 gather) ----------------
__global__ __launch_bounds__(256) void k_agg2(const uint2* __restrict__ hwb, const int2* __restrict__ epack,
                                              const int* __restrict__ off, const int* __restrict__ deg,
                                              const float* __restrict__ dinv, const float* __restrict__ b,
                                              float* __restrict__ out, int N) {
    const int node = blockIdx.x * 4 + (threadIdx.x >> 6);
    if (node >= N) return;
    const int lane = threadIdx.x & 63;
    const int grp  = lane >> 4;          // 0..3
    const int lc   = lane & 15;          // uint2 index within row
    const int c0   = lc << 2;            // first of 4 cols

    float4 acc0 = {0,0,0,0}, acc1 = {0,0,0,0}, acc2 = {0,0,0,0}, acc3 = {0,0,0,0};
    if (grp == 0) {
        float di = dinv[node];
        float w0 = di * di;
        uint2  sv = hwb[(size_t)node * 16 + lc];
        float4 bb = *(const float4*)&b[c0];
        acc0.x = bb.x + bf_lo(sv.x) * w0; acc0.y = bb.y + bf_hi(sv.x) * w0;
        acc0.z = bb.z + bf_lo(sv.y) * w0; acc0.w = bb.w + bf_hi(sv.y) * w0;
    }

    const int base = off[node];
    const int cnt  = deg[node] - 1;
    for (int p0 = 0; p0 < cnt; p0 += 64) {
        int2 ep = make_int2(0, 0);
        if (p0 + lane < cnt) ep = epack[base + p0 + lane];
        const int take = min(64, cnt - p0);
        int j = 0;
        for (; j + 16 <= take; j += 16) {
            int i0 = j + grp, i1 = j + 4 + grp, i2 = j + 8 + grp, i3 = j + 12 + grp;
            int   s0 = __shfl(ep.x, i0); float w0f = __int_as_float(__shfl(ep.y, i0));
            int   s1 = __shfl(ep.x, i1); float w1f = __int_as_float(__shfl(ep.y, i1));
            int   s2 = __shfl(ep.x, i2); float w2f = __int_as_float(__shfl(ep.y, i2));
            int   s3 = __shfl(ep.x, i3); float w3f = __int_as_float(__shfl(ep.y, i3));
            uint2 v0 = hwb[(size_t)s0 * 16 + lc];
            uint2 v1 = hwb[(size_t)s1 * 16 + lc];
            uint2 v2 = hwb[(size_t)s2 * 16 + lc];
            uint2 v3 = hwb[(size_t)s3 * 16 + lc];
            acc0.x += bf_lo(v0.x) * w0f; acc0.y += bf_hi(v0.x) * w0f;
            acc0.z += bf_lo(v0.y) * w0f; acc0.w += bf_hi(v0.y) * w0f;
            acc1.x += bf_lo(v1.x) * w1f; acc1.y += bf_hi(v1.x) * w1f;
            acc1.z += bf_lo(v1.y) * w1f; acc1.w += bf_hi(v1.y) * w1f;
            acc2.x += bf_lo(v2.x) * w2f; acc2.y += bf_hi(v2.x) * w2f;
            acc2.z += bf_lo(v2.y) * w2f; acc2.w += bf_hi(v2.y) * w2f;
            acc3.x += bf_lo(v3.x) * w3f; acc3.y += bf_hi(v3.x) * w3f;
            acc3.z += bf_lo(v3.y) * w3f; acc3.w += bf_hi(v3.y) * w3f;
        }
        for (; j < take; j += 4) {
            int i0 = j + grp;            // may hit a sentinel lane (w=0) — safe
            int   s0 = __shfl(ep.x, i0); float w0f = __int_as_float(__shfl(ep.y, i0));
            uint2 v0 = hwb[(size_t)s0 * 16 + lc];
            acc0.x += bf_lo(v0.x) * w0f; acc0.y += bf_hi(v0.x) * w0f;
            acc0.z += bf_lo(v0.y) * w0f; acc0.w += bf_hi(v0.y) * w0f;
        }
    }
    acc0.x += acc1.x + acc2.x + acc3.x;
    acc0.y += acc1.y + acc2.y + acc3.y;
    acc0.z += acc1.z + acc2.z + acc3.z;
    acc0.w += acc1.w + acc2.w + acc3.w;
    acc0.x += __shfl_xor(acc0.x, 16); acc0.y += __shfl_xor(acc0.y, 16);
    acc0.z += __shfl_xor(acc0.z, 16); acc0.w += __shfl_xor(acc0.w, 16);
    acc0.x += __shfl_xor(acc0.x, 32); acc0.y += __shfl_xor(acc0.y, 32);
    acc0.z += __shfl_xor(acc0.z, 32); acc0.w += __shfl_xor(acc0.w, 32);
    if (lane < 16) *(float4*)&out[(size_t)node * 64 + c0] = acc0;
}

extern "C" void kernel_launch(void* const* d_in, const int* in_sizes, int n_in,
                              void* d_out, int out_size, void* d_ws, size_t ws_size,
                              hipStream_t stream) {
    const float* x  = (const float*)d_in[0];
    const int*   ei = (const int*)  d_in[1];
    const float* W1 = (const float*)d_in[2];
    const float* b1 = (const float*)d_in[3];
    const float* W2 = (const float*)d_in[4];
    const float* b2 = (const float*)d_in[5];
    float* out = (float*)d_out;

    const int N = in_sizes[0] / 128;   // 50000
    const int E = in_sizes[1] / 2;     // 1600000
    const int* src = ei;
    const int* dst = ei + E;
    const int NB    = (N + 255) / 256;        // scan blocks (196)
    const int NBUCK = (N + 127) / 128;        // 391 (assumes <= 512)
    const int NA    = (E + ACHUNK - 1) / ACHUNK;

    // workspace layout:
    // deg[N] | dinv[N] | off[N] | partial[256] | bstart[512] | bcnt[512] | bcur[512]
    // | epack[E] int2 | xwb[N*128] bf16 | out1[N*128] f32 (aliases tmp[E] int2) | hwb[N*64] bf16
    char* w = (char*)d_ws;
    int*      deg     = (int*)w;              w += (size_t)N * 4;
    float*    dinv    = (float*)w;            w += (size_t)N * 4;
    int*      off     = (int*)w;              w += (size_t)N * 4;
    int*      partial = (int*)w;              w += 256 * 4;
    int*      bstart  = (int*)w;              w += 512 * 4;
    int*      bcnt    = (int*)w;              w += 512 * 4;
    int*      bcur    = (int*)w;              w += 512 * 4;
    int2*     epack   = (int2*)w;             w += (size_t)E * 8;
    unsigned* xwb     = (unsigned*)w;         w += (size_t)N * 128 * 2;
    float*    out1    = (float*)w;            w += (size_t)N * 128 * 4;
    unsigned* hwb     = (unsigned*)w;
    int2*     tmp     = (int2*)out1;          // tmp dead before agg1 writes out1

    // --- graph preprocessing (every call; deterministic workload) ---
    k_deg_init <<<NB, 256, 0, stream>>>(deg, N);
    k_deg_count<<<(E + 255) / 256, 256, 0, stream>>>(dst, deg, E);
    k_scan1    <<<NB, 256, 0, stream>>>(deg, dinv, off, partial, N);
    k_scan2    <<<1, 256, 0, stream>>>(partial, NB);
    k_scan3    <<<NB, 256, 0, stream>>>(off, partial, N);
    k_bparam   <<<(NBUCK + 255) / 256, 256, 0, stream>>>(off, bstart, bcnt, bcur, N, E, NBUCK);
    k_passA    <<<NA, 256, 0, stream>>>(src, dst, bcur, tmp, E, NBUCK);
    k_passB    <<<NBUCK, 256, 0, stream>>>(tmp, bstart, bcnt, off, dinv, epack, N);

    // --- layer 1 ---
    k_gemm1 <<<(N + 31) / 32, 256, 0, stream>>>(x, W1, xwb, N);
    k_agg1  <<<(N + 3) / 4, 256, 0, stream>>>((const uint2*)xwb, epack, off, deg, dinv, b1, out1, N);

    // --- layer 2 ---
    k_gemm2 <<<(N + 31) / 32, 256, 0, stream>>>(out1, W2, hwb, N);
    k_agg2  <<<(N + 3) / 4, 256, 0, stream>>>((const uint2*)hwb, epack, off, deg, dinv, b2, out, N);
}

// Round 8
// 248.706 us; speedup vs baseline: 1.5049x; 1.2718x over previous
//
#include <hip/hip_runtime.h>
#include <cstddef>

#define MAXB 512      // max coarse buckets (N<=65536 at 128 nodes/bucket)
#define BSHIFT 7      // 128 dst nodes per bucket
#define ACHUNK 8192   // edges per passA/histA block

// ---- bf16 pack/unpack helpers (RNE) ----
__device__ inline unsigned pack_bf16x2(float a, float b) {
    unsigned ua = __float_as_uint(a), ub = __float_as_uint(b);
    ua = (ua + 0x7FFFu + ((ua >> 16) & 1u)) >> 16;
    ub = (ub + 0x7FFFu + ((ub >> 16) & 1u)) >> 16;
    return ua | (ub << 16);
}
__device__ inline float bf_lo(unsigned u) { return __uint_as_float(u << 16); }
__device__ inline float bf_hi(unsigned u) { return __uint_as_float(u & 0xFFFF0000u); }

// ---------------- zero the bucket-count table ----------------
__global__ __launch_bounds__(512) void k_zero512(int* __restrict__ p) {
    p[threadIdx.x] = 0;
}

// ---------------- histA: global per-bucket edge counts ----------------
__global__ __launch_bounds__(256) void k_histA(const int* __restrict__ dst, int* __restrict__ bcnt,
                                               int E, int nbuck) {
    __shared__ int hist[MAXB];
    const int tid = threadIdx.x;
    const int e0  = blockIdx.x * ACHUNK;
    const int e1  = min(e0 + ACHUNK, E);
    for (int i = tid; i < nbuck; i += 256) hist[i] = 0;
    __syncthreads();
    for (int e = e0 + tid; e < e1; e += 256)
        atomicAdd(&hist[dst[e] >> BSHIFT], 1);
    __syncthreads();
    for (int i = tid; i < nbuck; i += 256)
        if (hist[i]) atomicAdd(&bcnt[i], hist[i]);
}

// ---------------- bscan: exclusive scan of bcnt -> bstart; bcur = bstart ----------------
__global__ __launch_bounds__(512) void k_bscan(const int* __restrict__ bcnt, int* __restrict__ bstart,
                                               int* __restrict__ bcur) {
    __shared__ int sh[512];
    const int t = threadIdx.x;
    int v = bcnt[t];
    sh[t] = v;
    __syncthreads();
    for (int d = 1; d < 512; d <<= 1) {
        int u = (t >= d) ? sh[t - d] : 0;
        __syncthreads();
        sh[t] += u;
        __syncthreads();
    }
    int ex = sh[t] - v;
    bstart[t] = ex;
    bcur[t]   = ex;
}

// ---------------- pass A: coarse split into bucket runs (block-owned reservations) ----------------
__global__ __launch_bounds__(256) void k_passA(const int* __restrict__ src, const int* __restrict__ dst,
                                               int* __restrict__ bcur, int2* __restrict__ tmp,
                                               int E, int nbuck) {
    __shared__ int hist[MAXB];
    __shared__ int gbase[MAXB];
    const int tid = threadIdx.x;
    const int e0  = blockIdx.x * ACHUNK;
    const int e1  = min(e0 + ACHUNK, E);
    for (int i = tid; i < nbuck; i += 256) hist[i] = 0;
    __syncthreads();
    for (int e = e0 + tid; e < e1; e += 256)
        atomicAdd(&hist[dst[e] >> BSHIFT], 1);
    __syncthreads();
    for (int i = tid; i < nbuck; i += 256) {
        int c = hist[i];
        gbase[i] = c ? atomicAdd(&bcur[i], c) : 0;
        hist[i] = 0;                       // reuse as local cursor
    }
    __syncthreads();
    for (int e = e0 + tid; e < e1; e += 256) {
        int d = dst[e];
        int b = d >> BSHIFT;
        int slot = atomicAdd(&hist[b], 1);
        tmp[gbase[b] + slot] = make_int2(src[e], d);
    }
}

// ---------------- pass B: derive deg/dinv/off + exact placement ----------------
// Bucket b owns nodes [node0, node0+128) and tmp run [base, base+cntB).
// Computes per-node counts in LDS, writes deg/dinv/off coalesced, places esrc.
__global__ __launch_bounds__(256) void k_passB(const int2* __restrict__ tmp, const int* __restrict__ bstart,
                                               const int* __restrict__ bcnt, int* __restrict__ deg,
                                               float* __restrict__ dinv, int* __restrict__ off,
                                               int* __restrict__ esrc, int N) {
    __shared__ int cnt[1 << BSHIFT];
    __shared__ int loff[1 << BSHIFT];
    __shared__ int cur[1 << BSHIFT];
    const int b     = blockIdx.x;
    const int tid   = threadIdx.x;
    const int node0 = b << BSHIFT;
    const int base  = bstart[b];
    const int cntB  = bcnt[b];

    if (tid < 128) cnt[tid] = 0;
    __syncthreads();
    for (int i = tid; i < cntB; i += 256)
        atomicAdd(&cnt[tmp[base + i].y - node0], 1);
    __syncthreads();
    if (tid < 128) loff[tid] = cnt[tid];
    __syncthreads();
    for (int d = 1; d < 128; d <<= 1) {
        int u = (tid >= d && tid < 128) ? loff[tid - d] : 0;
        __syncthreads();
        if (tid < 128) loff[tid] += u;
        __syncthreads();
    }
    if (tid < 128) {
        int c  = cnt[tid];
        int ex = loff[tid] - c;            // exclusive scan
        cur[tid] = ex;
        if (node0 + tid < N) {
            deg [node0 + tid] = c + 1;     // +1 self-loop
            dinv[node0 + tid] = rsqrtf((float)(c + 1));
            off [node0 + tid] = base + ex;
        }
    }
    __syncthreads();
    for (int i = tid; i < cntB; i += 256) {
        int2 ent = tmp[base + i];
        int  pos = atomicAdd(&cur[ent.y - node0], 1);
        esrc[base + pos] = ent.x;
    }
}

// ---------------- GEMM1: xwb[M,128](bf16) = x[M,128] @ W[128,128] ----------------
__global__ __launch_bounds__(256) void k_gemm1(const float* __restrict__ x, const float* __restrict__ W,
                                               unsigned* __restrict__ xwb, int M) {
    __shared__ float ws[128 * 128];      // ws[k*128 + c]
    __shared__ float xs[128][32];        // xs[k][r]  (transposed tile)
    const int tid  = threadIdx.x;
    const int row0 = blockIdx.x * 32;

    for (int i = tid * 4; i < 128 * 128; i += 1024)
        *(float4*)&ws[i] = *(const float4*)&W[i];

    for (int i = tid; i < 32 * 32; i += 256) {
        int r  = i >> 5;
        int cc = (i & 31) << 2;
        float4 v = make_float4(0.f, 0.f, 0.f, 0.f);
        if (row0 + r < M) v = *(const float4*)&x[(size_t)(row0 + r) * 128 + cc];
        xs[cc + 0][r] = v.x; xs[cc + 1][r] = v.y; xs[cc + 2][r] = v.z; xs[cc + 3][r] = v.w;
    }
    __syncthreads();

    const int c0 = (tid & 31) << 2;      // 4 cols
    const int r0 = (tid >> 5) << 2;      // 4 rows
    float4 a0 = {0,0,0,0}, a1 = {0,0,0,0}, a2 = {0,0,0,0}, a3 = {0,0,0,0};
#pragma unroll 8
    for (int k = 0; k < 128; ++k) {
        float4 wv = *(const float4*)&ws[k * 128 + c0];
        float4 xv = *(const float4*)&xs[k][r0];
        a0.x += xv.x * wv.x; a0.y += xv.x * wv.y; a0.z += xv.x * wv.z; a0.w += xv.x * wv.w;
        a1.x += xv.y * wv.x; a1.y += xv.y * wv.y; a1.z += xv.y * wv.z; a1.w += xv.y * wv.w;
        a2.x += xv.z * wv.x; a2.y += xv.z * wv.y; a2.z += xv.z * wv.z; a2.w += xv.z * wv.w;
        a3.x += xv.w * wv.x; a3.y += xv.w * wv.y; a3.z += xv.w * wv.z; a3.w += xv.w * wv.w;
    }
    uint2* o = (uint2*)xwb;
    if (row0 + r0 + 0 < M) o[(size_t)(row0 + r0 + 0) * 32 + (c0 >> 2)] = make_uint2(pack_bf16x2(a0.x, a0.y), pack_bf16x2(a0.z, a0.w));
    if (row0 + r0 + 1 < M) o[(size_t)(row0 + r0 + 1) * 32 + (c0 >> 2)] = make_uint2(pack_bf16x2(a1.x, a1.y), pack_bf16x2(a1.z, a1.w));
    if (row0 + r0 + 2 < M) o[(size_t)(row0 + r0 + 2) * 32 + (c0 >> 2)] = make_uint2(pack_bf16x2(a2.x, a2.y), pack_bf16x2(a2.z, a2.w));
    if (row0 + r0 + 3 < M) o[(size_t)(row0 + r0 + 3) * 32 + (c0 >> 2)] = make_uint2(pack_bf16x2(a3.x, a3.y), pack_bf16x2(a3.z, a3.w));
}

// ---------------- GEMM2: hwb[M,64](bf16) = relu(h[M,128]) @ W[128,64] ----------------
__global__ __launch_bounds__(256) void k_gemm2(const float* __restrict__ h_in, const float* __restrict__ W,
                                               unsigned* __restrict__ hwb, int M) {
    __shared__ float ws[128 * 64];       // ws[k*64 + c]
    __shared__ float xs[128][32];        // xs[k][r]
    const int tid  = threadIdx.x;
    const int row0 = blockIdx.x * 32;

    for (int i = tid * 4; i < 128 * 64; i += 1024)
        *(float4*)&ws[i] = *(const float4*)&W[i];

    for (int i = tid; i < 32 * 32; i += 256) {
        int r  = i >> 5;
        int cc = (i & 31) << 2;
        float4 v = make_float4(0.f, 0.f, 0.f, 0.f);
        if (row0 + r < M) {
            v = *(const float4*)&h_in[(size_t)(row0 + r) * 128 + cc];
            v.x = fmaxf(v.x, 0.f); v.y = fmaxf(v.y, 0.f);
            v.z = fmaxf(v.z, 0.f); v.w = fmaxf(v.w, 0.f);
        }
        xs[cc + 0][r] = v.x; xs[cc + 1][r] = v.y; xs[cc + 2][r] = v.z; xs[cc + 3][r] = v.w;
    }
    __syncthreads();

    const int c0 = (tid & 15) << 2;      // 4 cols of 64
    const int r0 = (tid >> 4) << 1;      // 2 rows
    float4 a0 = {0,0,0,0}, a1 = {0,0,0,0};
#pragma unroll 8
    for (int k = 0; k < 128; ++k) {
        float4 wv = *(const float4*)&ws[k * 64 + c0];
        float2 xv = *(const float2*)&xs[k][r0];
        a0.x += xv.x * wv.x; a0.y += xv.x * wv.y; a0.z += xv.x * wv.z; a0.w += xv.x * wv.w;
        a1.x += xv.y * wv.x; a1.y += xv.y * wv.y; a1.z += xv.y * wv.z; a1.w += xv.y * wv.w;
    }
    uint2* o = (uint2*)hwb;
    if (row0 + r0 + 0 < M) o[(size_t)(row0 + r0 + 0) * 16 + (c0 >> 2)] = make_uint2(pack_bf16x2(a0.x, a0.y), pack_bf16x2(a0.z, a0.w));
    if (row0 + r0 + 1 < M) o[(size_t)(row0 + r0 + 1) * 16 + (c0 >> 2)] = make_uint2(pack_bf16x2(a1.x, a1.y), pack_bf16x2(a1.z, a1.w));
}

// ---------------- pull aggregation, layer1 (bf16 gather, 4B edge entries) ----------------
__global__ __launch_bounds__(256) void k_agg1(const uint2* __restrict__ xwb, const int* __restrict__ esrc,
                                              const int* __restrict__ off, const int* __restrict__ deg,
                                              const float* __restrict__ dinv, const float* __restrict__ b,
                                              float* __restrict__ out1, int N) {
    const int node = blockIdx.x * 4 + (threadIdx.x >> 6);
    if (node >= N) return;
    const int lane = threadIdx.x & 63;
    const int half = lane >> 5;          // 0 or 1
    const int lc   = lane & 31;          // uint2 index within row
    const int c0   = lc << 2;            // first of 4 cols

    const float di = dinv[node];
    float4 acc0 = {0,0,0,0}, acc1 = {0,0,0,0}, acc2 = {0,0,0,0}, acc3 = {0,0,0,0};
    if (half == 0) {                     // self-loop + bias on half 0 only
        float w0 = di * di;
        uint2  sv = xwb[(size_t)node * 32 + lc];
        float4 bb = *(const float4*)&b[c0];
        acc0.x = bb.x + bf_lo(sv.x) * w0; acc0.y = bb.y + bf_hi(sv.x) * w0;
        acc0.z = bb.z + bf_lo(sv.y) * w0; acc0.w = bb.w + bf_hi(sv.y) * w0;
    }

    const int base = off[node];
    const int cnt  = deg[node] - 1;      // real (non-self) in-edges
    for (int p0 = 0; p0 < cnt; p0 += 64) {
        int   es = 0;                    // sentinel: row 0
        float ew = 0.f;                  // sentinel: weight 0
        if (p0 + lane < cnt) {
            es = esrc[base + p0 + lane];
            ew = dinv[es] * di;
        }
        const int take = min(64, cnt - p0);
        int j = 0;
        for (; j + 8 <= take; j += 8) {
            int i0 = j + half, i1 = j + 2 + half, i2 = j + 4 + half, i3 = j + 6 + half;
            int   s0 = __shfl(es, i0); float w0f = __shfl(ew, i0);
            int   s1 = __shfl(es, i1); float w1f = __shfl(ew, i1);
            int   s2 = __shfl(es, i2); float w2f = __shfl(ew, i2);
            int   s3 = __shfl(es, i3); float w3f = __shfl(ew, i3);
            uint2 v0 = xwb[(size_t)s0 * 32 + lc];
            uint2 v1 = xwb[(size_t)s1 * 32 + lc];
            uint2 v2 = xwb[(size_t)s2 * 32 + lc];
            uint2 v3 = xwb[(size_t)s3 * 32 + lc];
            acc0.x += bf_lo(v0.x) * w0f; acc0.y += bf_hi(v0.x) * w0f;
            acc0.z += bf_lo(v0.y) * w0f; acc0.w += bf_hi(v0.y) * w0f;
            acc1.x += bf_lo(v1.x) * w1f; acc1.y += bf_hi(v1.x) * w1f;
            acc1.z += bf_lo(v1.y) * w1f; acc1.w += bf_hi(v1.y) * w1f;
            acc2.x += bf_lo(v2.x) * w2f; acc2.y += bf_hi(v2.x) * w2f;
            acc2.z += bf_lo(v2.y) * w2f; acc2.w += bf_hi(v2.y) * w2f;
            acc3.x += bf_lo(v3.x) * w3f; acc3.y += bf_hi(v3.x) * w3f;
            acc3.z += bf_lo(v3.y) * w3f; acc3.w += bf_hi(v3.y) * w3f;
        }
        for (; j < take; j += 2) {
            int i0 = j + half;           // may hit a sentinel lane (w=0) — safe
            int   s0 = __shfl(es, i0); float w0f = __shfl(ew, i0);
            uint2 v0 = xwb[(size_t)s0 * 32 + lc];
            acc0.x += bf_lo(v0.x) * w0f; acc0.y += bf_hi(v0.x) * w0f;
            acc0.z += bf_lo(v0.y) * w0f; acc0.w += bf_hi(v0.y) * w0f;
        }
    }
    acc0.x += acc1.x + acc2.x + acc3.x;
    acc0.y += acc1.y + acc2.y + acc3.y;
    acc0.z += acc1.z + acc2.z + acc3.z;
    acc0.w += acc1.w + acc2.w + acc3.w;
    acc0.x += __shfl_xor(acc0.x, 32);
    acc0.y += __shfl_xor(acc0.y, 32);
    acc0.z += __shfl_xor(acc0.z, 32);
    acc0.w += __shfl_xor(acc0.w, 32);
    if (half == 0) *(float4*)&out1[(size_t)node * 128 + c0] = acc0;
}

// ---------------- pull aggregation, layer2 (bf16 gather, 4B edge entries) ----------------
__global__ __launch_bounds__(256) void k_agg2(const uint2* __restrict__ hwb, const int* __restrict__ esrc,
                                              const int* __restrict__ off, const int* __restrict__ deg,
                                              const float* __restrict__ dinv, const float* __restrict__ b,
                                              float* __restrict__ out, int N) {
    const int node = blockIdx.x * 4 + (threadIdx.x >> 6);
    if (node >= N) return;
    const int lane = threadIdx.x & 63;
    const int grp  = lane >> 4;          // 0..3
    const int lc   = lane & 15;          // uint2 index within row
    const int c0   = lc << 2;            // first of 4 cols

    const float di = dinv[node];
    float4 acc0 = {0,0,0,0}, acc1 = {0,0,0,0}, acc2 = {0,0,0,0}, acc3 = {0,0,0,0};
    if (grp == 0) {
        float w0 = di * di;
        uint2  sv = hwb[(size_t)node * 16 + lc];
        float4 bb = *(const float4*)&b[c0];
        acc0.x = bb.x + bf_lo(sv.x) * w0; acc0.y = bb.y + bf_hi(sv.x) * w0;
        acc0.z = bb.z + bf_lo(sv.y) * w0; acc0.w = bb.w + bf_hi(sv.y) * w0;
    }

    const int base = off[node];
    const int cnt  = deg[node] - 1;
    for (int p0 = 0; p0 < cnt; p0 += 64) {
        int   es = 0;
        float ew = 0.f;
        if (p0 + lane < cnt) {
            es = esrc[base + p0 + lane];
            ew = dinv[es] * di;
        }
        const int take = min(64, cnt - p0);
        int j = 0;
        for (; j + 16 <= take; j += 16) {
            int i0 = j + grp, i1 = j + 4 + grp, i2 = j + 8 + grp, i3 = j + 12 + grp;
            int   s0 = __shfl(es, i0); float w0f = __shfl(ew, i0);
            int   s1 = __shfl(es, i1); float w1f = __shfl(ew, i1);
            int   s2 = __shfl(es, i2); float w2f = __shfl(ew, i2);
            int   s3 = __shfl(es, i3); float w3f = __shfl(ew, i3);
            uint2 v0 = hwb[(size_t)s0 * 16 + lc];
            uint2 v1 = hwb[(size_t)s1 * 16 + lc];
            uint2 v2 = hwb[(size_t)s2 * 16 + lc];
            uint2 v3 = hwb[(size_t)s3 * 16 + lc];
            acc0.x += bf_lo(v0.x) * w0f; acc0.y += bf_hi(v0.x) * w0f;
            acc0.z += bf_lo(v0.y) * w0f; acc0.w += bf_hi(v0.y) * w0f;
            acc1.x += bf_lo(v1.x) * w1f; acc1.y += bf_hi(v1.x) * w1f;
            acc1.z += bf_lo(v1.y) * w1f; acc1.w += bf_hi(v1.y) * w1f;
            acc2.x += bf_lo(v2.x) * w2f; acc2.y += bf_hi(v2.x) * w2f;
            acc2.z += bf_lo(v2.y) * w2f; acc2.w += bf_hi(v2.y) * w2f;
            acc3.x += bf_lo(v3.x) * w3f; acc3.y += bf_hi(v3.x) * w3f;
            acc3.z += bf_lo(v3.y) * w3f; acc3.w += bf_hi(v3.y) * w3f;
        }
        for (; j < take; j += 4) {
            int i0 = j + grp;            // may hit a sentinel lane (w=0) — safe
            int   s0 = __shfl(es, i0); float w0f = __shfl(ew, i0);
            uint2 v0 = hwb[(size_t)s0 * 16 + lc];
            acc0.x += bf_lo(v0.x) * w0f; acc0.y += bf_hi(v0.x) * w0f;
            acc0.z += bf_lo(v0.y) * w0f; acc0.w += bf_hi(v0.y) * w0f;
        }
    }
    acc0.x += acc1.x + acc2.x + acc3.x;
    acc0.y += acc1.y + acc2.y + acc3.y;
    acc0.z += acc1.z + acc2.z + acc3.z;
    acc0.w += acc1.w + acc2.w + acc3.w;
    acc0.x += __shfl_xor(acc0.x, 16); acc0.y += __shfl_xor(acc0.y, 16);
    acc0.z += __shfl_xor(acc0.z, 16); acc0.w += __shfl_xor(acc0.w, 16);
    acc0.x += __shfl_xor(acc0.x, 32); acc0.y += __shfl_xor(acc0.y, 32);
    acc0.z += __shfl_xor(acc0.z, 32); acc0.w += __shfl_xor(acc0.w, 32);
    if (lane < 16) *(float4*)&out[(size_t)node * 64 + c0] = acc0;
}

extern "C" void kernel_launch(void* const* d_in, const int* in_sizes, int n_in,
                              void* d_out, int out_size, void* d_ws, size_t ws_size,
                              hipStream_t stream) {
    const float* x  = (const float*)d_in[0];
    const int*   ei = (const int*)  d_in[1];
    const float* W1 = (const float*)d_in[2];
    const float* b1 = (const float*)d_in[3];
    const float* W2 = (const float*)d_in[4];
    const float* b2 = (const float*)d_in[5];
    float* out = (float*)d_out;

    const int N = in_sizes[0] / 128;   // 50000
    const int E = in_sizes[1] / 2;     // 1600000
    const int* src = ei;
    const int* dst = ei + E;
    const int NBUCK = (N + 127) / 128;        // 391 (assumes <= 512)
    const int NA    = (E + ACHUNK - 1) / ACHUNK;

    // workspace layout:
    // deg[N] | dinv[N] | off[N] | bstart[512] | bcnt[512] | bcur[512]
    // | esrc[E] int | xwb[N*128] bf16 | out1[N*128] f32 (aliases tmp[E] int2) | hwb[N*64] bf16
    char* w = (char*)d_ws;
    int*      deg     = (int*)w;              w += (size_t)N * 4;
    float*    dinv    = (float*)w;            w += (size_t)N * 4;
    int*      off     = (int*)w;              w += (size_t)N * 4;
    int*      bstart  = (int*)w;              w += 512 * 4;
    int*      bcnt    = (int*)w;              w += 512 * 4;
    int*      bcur    = (int*)w;              w += 512 * 4;
    int*      esrc    = (int*)w;              w += (size_t)E * 4;
    unsigned* xwb     = (unsigned*)w;         w += (size_t)N * 128 * 2;
    float*    out1    = (float*)w;            w += (size_t)N * 128 * 4;
    unsigned* hwb     = (unsigned*)w;
    int2*     tmp     = (int2*)out1;          // tmp dead before agg1 writes out1

    // --- graph preprocessing (every call; deterministic workload) ---
    k_zero512 <<<1, 512, 0, stream>>>(bcnt);
    k_histA   <<<NA, 256, 0, stream>>>(dst, bcnt, E, NBUCK);
    k_bscan   <<<1, 512, 0, stream>>>(bcnt, bstart, bcur);
    k_passA   <<<NA, 256, 0, stream>>>(src, dst, bcur, tmp, E, NBUCK);
    k_passB   <<<NBUCK, 256, 0, stream>>>(tmp, bstart, bcnt, deg, dinv, off, esrc, N);

    // --- layer 1 ---
    k_gemm1 <<<(N + 31) / 32, 256, 0, stream>>>(x, W1, xwb, N);
    k_agg1  <<<(N + 3) / 4, 256, 0, stream>>>((const uint2*)xwb, esrc, off, deg, dinv, b1, out1, N);

    // --- layer 2 ---
    k_gemm2 <<<(N + 31) / 32, 256, 0, stream>>>(out1, W2, hwb, N);
    k_agg2  <<<(N + 3) / 4, 256, 0, stream>>>((const uint2*)hwb, esrc, off, deg, dinv, b2, out, N);
}